// Round 8
// baseline (122.418 us; speedup 1.0000x reference)
//
#include <hip/hip_runtime.h>

#define NPTS    150000
#define KOBJ    192
#define PBLK    256      // k_prep blocks (= partial rows)
#define PREP_T  512
#define MAIN_PTB 293     // point-blocks: 293 * 512 pts = 150016 >= NPTS
#define KQ      48       // k_main: objects per k-quarter
#define MAIN_GRID (MAIN_PTB * 4)   // = 1172 (same as round 7 -> ws layout unchanged)

__device__ __forceinline__ float clipb(float b) {
    return fminf(fmaxf(b, 1e-4f), 1.0f - 1e-4f);
}

// ws layout (bytes) — NOTHING needs pre-zeroing (all fully written each launch):
// pKey  : u64 [KOBJ*PBLK]   @ 0           object-major rows
// pW    : f32 [KOBJ*PBLK]   @ OFF_PW
// pP    : f32 [KOBJ*PBLK]   @ OFF_PP
// nzS   : f32 [PBLK]        @ OFF_NZS
// nzC   : f32 [PBLK]        @ OFF_NZC
// mbA   : f32 [KOBJ]        @ OFF_MB
// payA  : f32 [KOBJ]        @ OFF_PAY
// exA   : f32 [KOBJ]        @ OFF_EX
// xaq   : float4 [KOBJ]     @ OFF_XAQ
// attP  : f32 [MAIN_GRID]   @ OFF_ATTP
// repP  : f32 [MAIN_GRID]   @ OFF_REPP
// tick  : u32               @ OFF_TICK   (zeroed by every k_prep block)
#define OFF_PW   (KOBJ * PBLK * 8)
#define OFF_PP   (OFF_PW  + KOBJ * PBLK * 4)
#define OFF_NZS  (OFF_PP  + KOBJ * PBLK * 4)
#define OFF_NZC  (OFF_NZS + PBLK * 4)
#define OFF_MB   (OFF_NZC + PBLK * 4)
#define OFF_PAY  (OFF_MB  + KOBJ * 4)
#define OFF_EX   (OFF_PAY + KOBJ * 4)
#define OFF_XAQ  (OFF_EX  + KOBJ * 4)
#define OFF_ATTP (OFF_XAQ + KOBJ * 16)
#define OFF_REPP (OFF_ATTP + MAIN_GRID * 4)
#define OFF_TICK (OFF_REPP + MAIN_GRID * 4)

// ---------------------------------------------------------------------------
// Kernel 1: per-point prep -> per-block partial rows. No global atomics.
// (unchanged from round 7 — measured-good)
// ---------------------------------------------------------------------------
__global__ __launch_bounds__(PREP_T) void k_prep(
        const float* __restrict__ pred_beta,
        const float* __restrict__ pred_energy,
        const float* __restrict__ pred_pos,
        const int*   __restrict__ t_idx,
        const float* __restrict__ t_energy,
        const float* __restrict__ t_pos,
        unsigned long long* __restrict__ pKey,
        float* __restrict__ pW,
        float* __restrict__ pP,
        float* __restrict__ nzS,
        float* __restrict__ nzC,
        unsigned int* __restrict__ tick) {
    __shared__ unsigned sBits[KOBJ], sIdx[KOBJ];
    __shared__ float sW[KOBJ], sP[KOBJ];
    __shared__ float sNs[PREP_T / 64], sNc[PREP_T / 64];
    const int tid = threadIdx.x;
    if (tid < KOBJ) { sBits[tid] = 0u; sIdx[tid] = 0xFFFFFFFFu; sW[tid] = 0.f; sP[tid] = 0.f; }
    __syncthreads();

    float nS = 0.f, nC = 0.f;
    const int i0 = blockIdx.x * PREP_T + tid;
    for (int i = i0; i < NPTS; i += PBLK * PREP_T) {
        const float b = clipb(pred_beta[i]);
        const int   t = t_idx[i];
        if (t >= 0) {
            atomicMax(&sBits[t], __float_as_uint(b));     // native u32 LDS atomic
            const float a = atanhf(b);
            const float w = a * a;
            const float pe = pred_energy[i], te = t_energy[i];
            const float el = (te - pe) * (te - pe) / (te * te);
            const float pp0 = pred_pos[2 * i],  pp1 = pred_pos[2 * i + 1];
            const float tp0 = t_pos[2 * i],     tp1 = t_pos[2 * i + 1];
            const float pl = (tp0 - pp0) * (tp0 - pp0) / (tp0 * tp0)
                           + (tp1 - pp1) * (tp1 - pp1) / (tp1 * tp1);
            atomicAdd(&sW[t], w);
            atomicAdd(&sP[t], w * (el + pl));
        } else {
            nS += b; nC += 1.f;
        }
    }
    __syncthreads();
    // pass B: first-index tie-break among max-beta holders (np.argmax semantics)
    for (int i = i0; i < NPTS; i += PBLK * PREP_T) {
        const int t = t_idx[i];
        if (t >= 0 && __float_as_uint(clipb(pred_beta[i])) == sBits[t])
            atomicMin(&sIdx[t], (unsigned)i);
    }
    for (int off = 32; off > 0; off >>= 1) {
        nS += __shfl_down(nS, off);
        nC += __shfl_down(nC, off);
    }
    if ((tid & 63) == 0) { sNs[tid >> 6] = nS; sNc[tid >> 6] = nC; }
    __syncthreads();

    if (tid < KOBJ) {
        // empty object: bits=0, idx=0xFFFFFFFF -> key == 0 exactly
        const unsigned long long key =
            ((unsigned long long)sBits[tid] << 32) |
            (unsigned long long)(0xFFFFFFFFu - sIdx[tid]);
        const size_t o = (size_t)tid * PBLK + blockIdx.x;
        pKey[o] = key;
        pW[o]   = sW[tid];
        pP[o]   = sP[tid];
    }
    if (tid == 0) {
        float s = 0.f, c = 0.f;
        for (int w = 0; w < PREP_T / 64; ++w) { s += sNs[w]; c += sNc[w]; }
        nzS[blockIdx.x] = s;
        nzC[blockIdx.x] = c;
        *tick = 0u;   // benign same-value race; visible to k_main at kernel boundary
    }
}

// ---------------------------------------------------------------------------
// Kernel 2: per-object reduce (coalesced rows); alpha gather; mb/pay/exists.
// (unchanged from round 7 — measured-good)
// ---------------------------------------------------------------------------
__global__ __launch_bounds__(64) void k_objs(
        const float* __restrict__ pred_beta,
        const float* __restrict__ pred_ccoords,
        const float* __restrict__ t_time,
        const unsigned long long* __restrict__ pKey,
        const float* __restrict__ pW,
        const float* __restrict__ pP,
        float4* __restrict__ xaq,
        float* __restrict__ mbA,
        float* __restrict__ payA,
        float* __restrict__ exA) {
    const int k = blockIdx.x, lane = threadIdx.x;
    const size_t row = (size_t)k * PBLK;
    unsigned long long best = 0ULL;
    float w = 0.f, pay = 0.f;
    #pragma unroll
    for (int p = lane; p < PBLK; p += 64) {
        const unsigned long long v = pKey[row + p];
        if (v > best) best = v;
        w   += pW[row + p];
        pay += pP[row + p];
    }
    for (int off = 32; off > 0; off >>= 1) {
        const unsigned long long ob = __shfl_down(best, off);
        if (ob > best) best = ob;
        w   += __shfl_down(w,   off);
        pay += __shfl_down(pay, off);
    }
    if (lane == 0) {
        float4 v = make_float4(0.f, 0.f, 0.f, 0.f);
        float mb = 0.f, pk = 0.f, ex = 0.f;
        if (best != 0ULL) {
            const unsigned ai = 0xFFFFFFFFu - (unsigned)(best & 0xFFFFFFFFull);
            const float b = clipb(pred_beta[ai]);
            const float a = atanhf(b);
            v.x = pred_ccoords[3 * ai];
            v.y = pred_ccoords[3 * ai + 1];
            v.z = pred_ccoords[3 * ai + 2];
            v.w = (a * a + 0.5f) * t_time[ai];   // q_alpha (0 if no object)
            mb = 1.0f - b;
            pk = pay / (w + 1e-9f);
            ex = 1.f;
        }
        xaq[k] = v; mbA[k] = mb; payA[k] = pk; exA[k] = ex;
    }
}

// ---------------------------------------------------------------------------
// Kernel 3: main loop — 2 points/thread x K-quarter per block.
// Each LDS broadcast read feeds TWO points' VALU work (halved LDS/VALU ratio).
// grid = MAIN_PTB * 4; last block combines everything.
// ---------------------------------------------------------------------------
__device__ __forceinline__ float rep_term(float x0, float x1, float x2,
                                          float a0, float a1, float a2, float qw) {
    const float d0 = x0 - a0, d1 = x1 - a1, d2 = x2 - a2;
    const float dd = d0 * d0 + d1 * d1 + d2 * d2 + 1e-9f;
    return fmaxf(1.0f - __builtin_amdgcn_sqrtf(dd), 0.f) * qw;
}

__device__ __forceinline__ float block_sum(float v, float* red, int tid) {
    for (int off = 32; off > 0; off >>= 1) v += __shfl_down(v, off);
    if ((tid & 63) == 0) red[tid >> 6] = v;
    __syncthreads();
    const float r = red[0] + red[1] + red[2] + red[3];
    __syncthreads();
    return r;
}

__global__ __launch_bounds__(256) void k_main(
        const float* __restrict__ pred_beta,
        const float* __restrict__ pred_ccoords,
        const int*   __restrict__ t_idx,
        const float* __restrict__ t_time,
        const float4* __restrict__ xaq,
        const float* __restrict__ nzS,
        const float* __restrict__ nzC,
        const float* __restrict__ mbA,
        const float* __restrict__ payA,
        const float* __restrict__ exA,
        float* __restrict__ attP,
        float* __restrict__ repP,
        unsigned int* __restrict__ tick,
        float* __restrict__ out) {
    __shared__ float s0[KQ], s1[KQ], s2[KQ], sq[KQ];
    __shared__ float red[4];
    __shared__ int sLast;
    const int tid = threadIdx.x;
    const int k0  = (blockIdx.x & 3) * KQ;
    if (tid < KQ) {
        const float4 v = xaq[k0 + tid];
        s0[tid] = v.x; s1[tid] = v.y; s2[tid] = v.z; sq[tid] = v.w;
    }
    __syncthreads();

    const int iA = (blockIdx.x >> 2) * 512 + tid;
    const int iB = iA + 256;
    float contrib = 0.f, attc = 0.f;

    // point A state
    float ax = 0.f, ay = 0.f, az = 0.f, aq_ = 0.f; int aj = -1; bool va = iA < NPTS;
    if (va) {
        ax = pred_ccoords[3 * iA]; ay = pred_ccoords[3 * iA + 1]; az = pred_ccoords[3 * iA + 2];
        const float b = clipb(pred_beta[iA]);
        const float a = atanhf(b);
        aq_ = (a * a + 0.5f) * t_time[iA];
        aj  = t_idx[iA] - k0;
    }
    // point B state
    float bx = 0.f, by = 0.f, bz = 0.f, bq_ = 0.f; int bj = -1; bool vb = iB < NPTS;
    if (vb) {
        bx = pred_ccoords[3 * iB]; by = pred_ccoords[3 * iB + 1]; bz = pred_ccoords[3 * iB + 2];
        const float b = clipb(pred_beta[iB]);
        const float a = atanhf(b);
        bq_ = (a * a + 0.5f) * t_time[iB];
        bj  = t_idx[iB] - k0;
    }

    float rA0 = 0.f, rA1 = 0.f, rB0 = 0.f, rB1 = 0.f;
    for (int kk = 0; kk < KQ; kk += 4) {
        const float c00 = s0[kk],     c01 = s1[kk],     c02 = s2[kk],     q0 = sq[kk];
        const float c10 = s0[kk + 1], c11 = s1[kk + 1], c12 = s2[kk + 1], q1 = sq[kk + 1];
        const float c20 = s0[kk + 2], c21 = s1[kk + 2], c22 = s2[kk + 2], q2 = sq[kk + 2];
        const float c30 = s0[kk + 3], c31 = s1[kk + 3], c32 = s2[kk + 3], q3 = sq[kk + 3];
        rA0 += rep_term(ax, ay, az, c00, c01, c02, q0);
        rA1 += rep_term(ax, ay, az, c10, c11, c12, q1);
        rA0 += rep_term(ax, ay, az, c20, c21, c22, q2);
        rA1 += rep_term(ax, ay, az, c30, c31, c32, q3);
        rB0 += rep_term(bx, by, bz, c00, c01, c02, q0);
        rB1 += rep_term(bx, by, bz, c10, c11, c12, q1);
        rB0 += rep_term(bx, by, bz, c20, c21, c22, q2);
        rB1 += rep_term(bx, by, bz, c30, c31, c32, q3);
    }
    if (va) {
        float rep = rA0 + rA1, att = 0.f;
        if (aj >= 0 && aj < KQ) {
            const float d0 = ax - s0[aj], d1 = ay - s1[aj], d2 = az - s2[aj];
            const float dd = d0 * d0 + d1 * d1 + d2 * d2;
            rep -= fmaxf(1.0f - __builtin_amdgcn_sqrtf(dd + 1e-9f), 0.f) * sq[aj];
            att  = dd * sq[aj];
        }
        contrib += rep * aq_; attc += att * aq_;
    }
    if (vb) {
        float rep = rB0 + rB1, att = 0.f;
        if (bj >= 0 && bj < KQ) {
            const float d0 = bx - s0[bj], d1 = by - s1[bj], d2 = bz - s2[bj];
            const float dd = d0 * d0 + d1 * d1 + d2 * d2;
            rep -= fmaxf(1.0f - __builtin_amdgcn_sqrtf(dd + 1e-9f), 0.f) * sq[bj];
            att  = dd * sq[bj];
        }
        contrib += rep * bq_; attc += att * bq_;
    }

    float rep = contrib, att = attc;
    for (int off = 32; off > 0; off >>= 1) {
        rep += __shfl_down(rep, off);
        att += __shfl_down(att, off);
    }
    __shared__ float wr[4], wa[4];
    const int wid = tid >> 6;
    if ((tid & 63) == 0) { wr[wid] = rep; wa[wid] = att; }
    __syncthreads();
    if (tid == 0) {
        attP[blockIdx.x] = wa[0] + wa[1] + wa[2] + wa[3];
        repP[blockIdx.x] = wr[0] + wr[1] + wr[2] + wr[3];
        __threadfence();
        const unsigned old = atomicAdd(tick, 1u);
        sLast = (old == MAIN_GRID - 1) ? 1 : 0;
    }
    __syncthreads();
    if (sLast) {
        // final combine: atomic-reads for intra-kernel partials (XCD coherence),
        // plain reads for prior-kernel outputs (kernel-boundary flushed).
        float aS = 0.f, rS = 0.f;
        for (int b = tid; b < MAIN_GRID; b += 256) {
            aS += atomicAdd(&attP[b], 0.f);
            rS += atomicAdd(&repP[b], 0.f);
        }
        float mb = 0.f, pay = 0.f, ex = 0.f;
        if (tid < KOBJ) { mb = mbA[tid]; pay = payA[tid]; ex = exA[tid]; }
        const float ns = nzS[tid];   // PBLK == 256 == blockDim
        const float nc = nzC[tid];

        const float attS = block_sum(aS, red, tid);
        const float repS = block_sum(rS, red, tid);
        const float mbS  = block_sum(mb, red, tid);
        const float payS = block_sum(pay, red, tid);
        const float exS  = block_sum(ex, red, tid);
        const float nSs  = block_sum(ns, red, tid);
        const float nCs  = block_sum(nc, red, tid);
        if (tid == 0) {
            const float n    = (float)NPTS;
            const float nobj = fmaxf(exS, 1.0f);
            out[0] = attS / n + repS / n + nSs / fmaxf(nCs, 1.0f)
                   + mbS / nobj + payS / nobj;
        }
    }
}

extern "C" void kernel_launch(void* const* d_in, const int* in_sizes, int n_in,
                              void* d_out, int out_size, void* d_ws, size_t ws_size,
                              hipStream_t stream) {
    const float* pred_beta    = (const float*)d_in[0];
    const float* pred_ccoords = (const float*)d_in[1];
    const float* pred_energy  = (const float*)d_in[2];
    const float* pred_pos     = (const float*)d_in[3];
    const int*   t_idx        = (const int*)  d_in[6];
    const float* t_energy     = (const float*)d_in[7];
    const float* t_pos        = (const float*)d_in[8];
    const float* t_time       = (const float*)d_in[9];

    char* ws = (char*)d_ws;
    unsigned long long* pKey = (unsigned long long*)ws;
    float*        pW   = (float*)(ws + OFF_PW);
    float*        pP   = (float*)(ws + OFF_PP);
    float*        nzS  = (float*)(ws + OFF_NZS);
    float*        nzC  = (float*)(ws + OFF_NZC);
    float*        mbA  = (float*)(ws + OFF_MB);
    float*        payA = (float*)(ws + OFF_PAY);
    float*        exA  = (float*)(ws + OFF_EX);
    float4*       xaq  = (float4*)(ws + OFF_XAQ);
    float*        attP = (float*)(ws + OFF_ATTP);
    float*        repP = (float*)(ws + OFF_REPP);
    unsigned int* tick = (unsigned int*)(ws + OFF_TICK);

    // no memset: every ws word used is fully written each launch.
    k_prep<<<PBLK, PREP_T, 0, stream>>>(pred_beta, pred_energy, pred_pos,
                                        t_idx, t_energy, t_pos,
                                        pKey, pW, pP, nzS, nzC, tick);
    k_objs<<<KOBJ, 64, 0, stream>>>(pred_beta, pred_ccoords, t_time,
                                    pKey, pW, pP, xaq, mbA, payA, exA);
    k_main<<<MAIN_GRID, 256, 0, stream>>>(pred_beta, pred_ccoords, t_idx, t_time,
                                          xaq, nzS, nzC, mbA, payA, exA,
                                          attP, repP, tick, (float*)d_out);
}